// Round 5
// baseline (373.025 us; speedup 1.0000x reference)
//
#include <hip/hip_runtime.h>
#include <stdint.h>

typedef unsigned short u16;
typedef __attribute__((ext_vector_type(8))) short bf16x8;
typedef __attribute__((ext_vector_type(4))) short s16x4;
typedef __attribute__((ext_vector_type(4))) float f32x4;

#define MFMA16(a,b,c) __builtin_amdgcn_mfma_f32_16x16x32_bf16((a),(b),(c),0,0,0)

__device__ __forceinline__ u16 f2bf(float f) {
  union { float f; uint32_t u; } v; v.f = f;
  return (u16)((v.u + 0x7fffu + ((v.u >> 16) & 1u)) >> 16);
}

// async 16B global->LDS (lds dest = wave-uniform base + lane*16)
__device__ __forceinline__ void gload16(const void* g, void* l) {
  __builtin_amdgcn_global_load_lds((const __attribute__((address_space(1))) void*)g,
                                   (__attribute__((address_space(3))) void*)l, 16, 0, 0);
}

// Stage a 128x64 bf16 tile into lds[128*64] with chunk-xor swizzle.
// Physical chunk (r, pc) holds logical chunk (r, pc^(r&7)).
__device__ __forceinline__ void stage256(const u16* src, size_t stride, u16* lds, int tid) {
#pragma unroll
  for (int i = 0; i < 4; ++i) {
    const int L = i * 256 + tid;       // chunk 0..1023
    const int r = L >> 3, pc = L & 7;
    const int lc = pc ^ (r & 7);
    gload16(src + (size_t)r * stride + lc * 8, lds + (size_t)(i * 256 + (tid & ~63)) * 8);
  }
}
__device__ __forceinline__ void stage512(const u16* src, size_t stride, u16* lds, int tid) {
#pragma unroll
  for (int i = 0; i < 2; ++i) {
    const int L = i * 512 + tid;
    const int r = L >> 3, pc = L & 7;
    const int lc = pc ^ (r & 7);
    gload16(src + (size_t)r * stride + lc * 8, lds + (size_t)(i * 512 + (tid & ~63)) * 8);
  }
}
// read logical chunk kc of row from a swizzled 128x64 tile
#define TILE_AT(lds, row, kc) \
  (*(const bf16x8*)&(lds)[((((row) << 3) + ((kc) ^ ((row) & 7)))) << 3])

// ---------- kernel 1: cast hidden_states fp32 -> bf16 ----------
__global__ void k_cast(const float* __restrict__ src, u16* __restrict__ dst, int n8) {
  int idx = blockIdx.x * 256 + threadIdx.x;
  if (idx >= n8) return;
  const float4* s = (const float4*)src + (size_t)idx * 2;
  float4 a = s[0], b = s[1];
  bf16x8 o;
  o[0] = (short)f2bf(a.x); o[1] = (short)f2bf(a.y);
  o[2] = (short)f2bf(a.z); o[3] = (short)f2bf(a.w);
  o[4] = (short)f2bf(b.x); o[5] = (short)f2bf(b.y);
  o[6] = (short)f2bf(b.z); o[7] = (short)f2bf(b.w);
  *(bf16x8*)(dst + (size_t)idx * 8) = o;
}

// ---------- kernel 2: transpose+cast weight: Wt[j][d] = bf16(W[d][j]) ----------
__global__ void k_wtrans(const float* __restrict__ W, u16* __restrict__ Wt) {
  __shared__ u16 tile[32][33];
  int bd = blockIdx.x >> 5, bj = blockIdx.x & 31;
  int tx = threadIdx.x & 31, ty = threadIdx.x >> 5;
#pragma unroll
  for (int i = 0; i < 32; i += 8)
    tile[ty + i][tx] = f2bf(W[(size_t)(bd * 32 + ty + i) * 1024 + bj * 32 + tx]);
  __syncthreads();
#pragma unroll
  for (int i = 0; i < 32; i += 8)
    Wt[(size_t)(bj * 32 + ty + i) * 1024 + bd * 32 + tx] = tile[tx][ty + i];
}

// ---------- kernel 3: zero output ----------
__global__ void k_zero(float4* __restrict__ p, int n4) {
  int idx = blockIdx.x * 256 + threadIdx.x;
  if (idx < n4) p[idx] = make_float4(0.f, 0.f, 0.f, 0.f);
}

// ---------- kernel 4: fused QKV GEMM (async LDS staging, NT epilogue) ----------
__global__ __launch_bounds__(256, 2) void k_qkv(
    const u16* __restrict__ hsb, const u16* __restrict__ Wt,
    const float* __restrict__ bq, const float* __restrict__ bk, const float* __restrict__ bv,
    u16* __restrict__ Qb, u16* __restrict__ Kb, u16* __restrict__ Vt) {
  __shared__ u16 a_lds[128 * 64];
  __shared__ u16 b_lds[128 * 64];
  const int tid = threadIdx.x;
  const int lane = tid & 63, wid = tid >> 6;
  const int l15 = lane & 15, quad = lane >> 4;
  const int wr = wid >> 1, wc = wid & 1;
  const int bx = blockIdx.x & 31;
  const int by = blockIdx.x >> 5;
  const int Mbase = bx * 128;
  const int widx = by >> 3;               // 0=Q 1=K 2=V
  const int Nloc = (by & 7) * 128;

  f32x4 acc[4][4];
#pragma unroll
  for (int i = 0; i < 4; ++i)
#pragma unroll
    for (int j = 0; j < 4; ++j) acc[i][j] = (f32x4){0.f, 0.f, 0.f, 0.f};

  const u16* asrc = hsb + (size_t)Mbase * 1024;
  const u16* bsrc = Wt + (size_t)widx * 1048576 + (size_t)Nloc * 1024;

  for (int kb = 0; kb < 16; ++kb) {
    __syncthreads();
    stage256(asrc + kb * 64, 1024, a_lds, tid);
    stage256(bsrc + kb * 64, 1024, b_lds, tid);
    __syncthreads();
#pragma unroll
    for (int ks = 0; ks < 2; ++ks) {
      const int kc = ks * 4 + quad;
      bf16x8 af[4], bfr[4];
#pragma unroll
      for (int mt = 0; mt < 4; ++mt) af[mt] = TILE_AT(a_lds, wr * 64 + mt * 16 + l15, kc);
#pragma unroll
      for (int nt = 0; nt < 4; ++nt) bfr[nt] = TILE_AT(b_lds, wc * 64 + nt * 16 + l15, kc);
#pragma unroll
      for (int mt = 0; mt < 4; ++mt)
#pragma unroll
        for (int nt = 0; nt < 4; ++nt)
          acc[mt][nt] = MFMA16(af[mt], bfr[nt], acc[mt][nt]);
    }
  }
  const float* bias = (widx == 0) ? bq : ((widx == 1) ? bk : bv);
#pragma unroll
  for (int nt = 0; nt < 4; ++nt) {
    const int jloc = Nloc + wc * 64 + nt * 16 + l15;
    const float bias_v = bias[jloc];
#pragma unroll
    for (int mt = 0; mt < 4; ++mt) {
      const int Mr0 = Mbase + wr * 64 + mt * 16 + quad * 4;
      if (widx == 2) {
        const int b = Mr0 >> 11, mseq = Mr0 & 2047;
        const int g = jloc >> 7, h = jloc & 127;
        s16x4 pk;
#pragma unroll
        for (int r = 0; r < 4; ++r) pk[r] = (short)f2bf(acc[mt][nt][r] + bias_v);
        __builtin_nontemporal_store(pk, (s16x4*)(Vt + (((size_t)b * 8 + g) * 128 + h) * 2048 + mseq));
      } else {
        u16* dst = (widx == 0) ? Qb : Kb;
#pragma unroll
        for (int r = 0; r < 4; ++r)
          __builtin_nontemporal_store(f2bf(acc[mt][nt][r] + bias_v),
                                      dst + (size_t)(Mr0 + r) * 1024 + jloc);
      }
    }
  }
}

// ---------- kernel 5: scores + softmax-over-g -> Pt[b][g][n][m-half] ----------
// grid 1024 = 8mt (XCD-pinned: same-K blocks share an XCD L2) x 64nt x 2b.
// 8 waves; wave owns 16 m rows. kf prefetch distance 2; Pt stores non-temporal
// (keep K resident in local L2 instead of being thrashed by the P stream).
__global__ __launch_bounds__(512, 4) void k_score(
    const u16* __restrict__ Qb, const u16* __restrict__ Kb,
    u16* __restrict__ Pt, int mh) {
  __shared__ u16 q_lds[32 * 1024];  // [n][h], 16B chunks xor-swizzled by (n&7)
  const int tid = threadIdx.x;
  const int w = tid >> 6;
  const int lane = tid & 63;
  const int l15 = lane & 15, quad = lane >> 4;
  const int bx = blockIdx.x;
  const int mt = bx & 7;
  const int nt = (bx >> 3) & 63;
  const int bcoord = bx >> 9;
  const int nbase = nt * 32;
  const int mloc = mt * 128;
  const int mglob = mh * 1024 + mloc;
  const size_t boff = (size_t)bcoord * 2048;

  // stage Q tile 32 x 1024
#pragma unroll
  for (int i = 0; i < 8; ++i) {
    int idx = tid + i * 512;
    int r = idx >> 7, c = idx & 127;
    bf16x8 v = *(const bf16x8*)(Qb + (boff + nbase + r) * 1024 + c * 8);
    *(bf16x8*)&q_lds[r * 1024 + ((c ^ (r & 7)) << 3)] = v;
  }
  __syncthreads();

  f32x4 sacc[2][8];
#pragma unroll
  for (int nf = 0; nf < 2; ++nf)
#pragma unroll
    for (int g = 0; g < 8; ++g) sacc[nf][g] = (f32x4){0.f, 0.f, 0.f, 0.f};

  const u16* kp = Kb + (boff + mglob + w * 16 + l15) * 1024 + quad * 8;
  bf16x8 kbuf[2][4];
#pragma unroll
  for (int ks = 0; ks < 4; ++ks) kbuf[0][ks] = *(const bf16x8*)(kp + ks * 32);
#pragma unroll
  for (int ks = 0; ks < 4; ++ks) kbuf[1][ks] = *(const bf16x8*)(kp + 128 + ks * 32);
#pragma unroll
  for (int g = 0; g < 8; ++g) {
#pragma unroll
    for (int ks = 0; ks < 4; ++ks) {
      const int hoff = g * 128 + ks * 32 + quad * 8;
#pragma unroll
      for (int nf = 0; nf < 2; ++nf) {
        const int row = nf * 16 + l15;
        bf16x8 qf = *(const bf16x8*)&q_lds[row * 1024 + (((hoff >> 3) ^ (row & 7)) << 3)];
        sacc[nf][g] = MFMA16(kbuf[g & 1][ks], qf, sacc[nf][g]);  // D[m][n]
      }
    }
    if (g < 6) {  // distance-2 prefetch into the buffer just consumed
#pragma unroll
      for (int ks = 0; ks < 4; ++ks)
        kbuf[g & 1][ks] = *(const bf16x8*)(kp + (g + 2) * 128 + ks * 32);
    }
  }
  // softmax over g (register-local)
#pragma unroll
  for (int nf = 0; nf < 2; ++nf)
#pragma unroll
    for (int r = 0; r < 4; ++r) {
      float s[8];
#pragma unroll
      for (int g = 0; g < 8; ++g) s[g] = sacc[nf][g][r] * 0.03125f;
      float mx = s[0];
#pragma unroll
      for (int g = 1; g < 8; ++g) mx = fmaxf(mx, s[g]);
      float sum = 0.f;
#pragma unroll
      for (int g = 0; g < 8; ++g) { s[g] = __expf(s[g] - mx); sum += s[g]; }
      const float rs = 1.0f / sum;
#pragma unroll
      for (int g = 0; g < 8; ++g) sacc[nf][g][r] = s[g] * rs;
    }
  // store Pt[b][g][n][m-half] non-temporally (bypass L2)
  const int mcol = mloc + w * 16 + quad * 4;
#pragma unroll
  for (int g = 0; g < 8; ++g) {
    const size_t gbase = ((size_t)(bcoord * 8 + g) * 2048) * 1024;
#pragma unroll
    for (int nf = 0; nf < 2; ++nf) {
      s16x4 pk;
#pragma unroll
      for (int r = 0; r < 4; ++r) pk[r] = (short)f2bf(sacc[nf][g][r]);
      __builtin_nontemporal_store(
          pk, (s16x4*)(Pt + gbase + (size_t)(nbase + nf * 16 + l15) * 1024 + mcol));
    }
  }
}

// ---------- kernel 6: PV GEMM, async LDS staging ----------
// grid 512 = 8g (XCD-pinned) x 2ksp x 16mt x 2b; 512 thr = 8 waves (4 wr x 2 wc).
__global__ __launch_bounds__(512, 4) void k_pv(
    const u16* __restrict__ Pt, const u16* __restrict__ Vt,
    float* __restrict__ out, int mh) {
  __shared__ u16 a_lds[128 * 64];
  __shared__ u16 b_lds[128 * 64];
  const int tid = threadIdx.x;
  const int lane = tid & 63, wid = tid >> 6;
  const int l15 = lane & 15, quad = lane >> 4;
  const int wr = wid >> 1, wc = wid & 1;
  const int bx = blockIdx.x;
  const int g = bx & 7;
  const int ksp = (bx >> 3) & 1;
  const int mt = (bx >> 4) & 15;
  const int bcoord = bx >> 8;
  const int nbase = mt * 128;
  const int kh0 = ksp * 512;

  const u16* asrc = Pt + (size_t)(bcoord * 8 + g) * 2048 * 1024 + (size_t)nbase * 1024 + kh0;
  const u16* bsrc = Vt + (size_t)(bcoord * 8 + g) * 128 * 2048 + mh * 1024 + kh0;

  f32x4 acc[2][4];
#pragma unroll
  for (int i = 0; i < 2; ++i)
#pragma unroll
    for (int j = 0; j < 4; ++j) acc[i][j] = (f32x4){0.f, 0.f, 0.f, 0.f};

  for (int kb = 0; kb < 8; ++kb) {
    __syncthreads();
    stage512(asrc + kb * 64, 1024, a_lds, tid);
    stage512(bsrc + kb * 64, 2048, b_lds, tid);
    __syncthreads();
#pragma unroll
    for (int ks = 0; ks < 2; ++ks) {
      const int kc = ks * 4 + quad;
      bf16x8 af[2], bfr[4];
#pragma unroll
      for (int mf = 0; mf < 2; ++mf) af[mf] = TILE_AT(a_lds, wr * 32 + mf * 16 + l15, kc);
#pragma unroll
      for (int nf = 0; nf < 4; ++nf) bfr[nf] = TILE_AT(b_lds, wc * 64 + nf * 16 + l15, kc);
#pragma unroll
      for (int mf = 0; mf < 2; ++mf)
#pragma unroll
        for (int nf = 0; nf < 4; ++nf)
          acc[mf][nf] = MFMA16(af[mf], bfr[nf], acc[mf][nf]);
    }
  }
#pragma unroll
  for (int mf = 0; mf < 2; ++mf)
#pragma unroll
    for (int nf = 0; nf < 4; ++nf)
#pragma unroll
      for (int r = 0; r < 4; ++r) {
        const int nrow = nbase + wr * 32 + mf * 16 + quad * 4 + r;
        const int col = g * 128 + wc * 64 + nf * 16 + l15;
        atomicAdd(out + ((size_t)bcoord * 2048 + nrow) * 1024 + col, acc[mf][nf][r]);
      }
}

extern "C" void kernel_launch(void* const* d_in, const int* in_sizes, int n_in,
                              void* d_out, int out_size, void* d_ws, size_t ws_size,
                              hipStream_t stream) {
  const float* hs = (const float*)d_in[0];
  const float* Wq = (const float*)d_in[1];
  const float* bq = (const float*)d_in[2];
  const float* Wk = (const float*)d_in[3];
  const float* bk = (const float*)d_in[4];
  const float* Wv = (const float*)d_in[5];
  const float* bv = (const float*)d_in[6];
  float* out = (float*)d_out;

  u16* ws = (u16*)d_ws;
  u16* hsb = ws;                   // 4096x1024
  u16* Wt  = ws + 4194304;         // 3 x 1024x1024 (j-major)
  u16* Qb  = ws + 7340032;         // [b][n][1024]
  u16* Kb  = ws + 11534336;        // [b][m][1024]
  u16* Vt  = ws + 15728640;        // [b][g][h][m] = [2][8][128][2048]
  u16* Pt  = ws + 19922944;        // [b][g][n][m-half] = [2][8][2048][1024]

  k_cast<<<2048, 256, 0, stream>>>(hs, hsb, 524288);
  k_wtrans<<<1024, 256, 0, stream>>>(Wq, Wt);
  k_wtrans<<<1024, 256, 0, stream>>>(Wk, Wt + 1048576);
  k_wtrans<<<1024, 256, 0, stream>>>(Wv, Wt + 2097152);
  k_qkv<<<32 * 24, 256, 0, stream>>>(hsb, Wt, bq, bk, bv, Qb, Kb, Vt);
  k_zero<<<4096, 256, 0, stream>>>((float4*)out, 1048576);
  for (int mh = 0; mh < 2; ++mh) {
    k_score<<<1024, 512, 0, stream>>>(Qb, Kb, Pt, mh);
    k_pv<<<512, 512, 0, stream>>>(Pt, Vt, out, mh);
  }
}

// Round 6
// 367.460 us; speedup vs baseline: 1.0151x; 1.0151x over previous
//
#include <hip/hip_runtime.h>
#include <stdint.h>

typedef unsigned short u16;
typedef __attribute__((ext_vector_type(8))) short bf16x8;
typedef __attribute__((ext_vector_type(4))) short s16x4;
typedef __attribute__((ext_vector_type(4))) float f32x4;

#define MFMA16(a,b,c) __builtin_amdgcn_mfma_f32_16x16x32_bf16((a),(b),(c),0,0,0)

__device__ __forceinline__ u16 f2bf(float f) {
  union { float f; uint32_t u; } v; v.f = f;
  return (u16)((v.u + 0x7fffu + ((v.u >> 16) & 1u)) >> 16);
}

// async 16B global->LDS (lds dest = wave-uniform base + lane*16)
__device__ __forceinline__ void gload16(const void* g, void* l) {
  __builtin_amdgcn_global_load_lds((const __attribute__((address_space(1))) void*)g,
                                   (__attribute__((address_space(3))) void*)l, 16, 0, 0);
}

// Stage a 128x64 bf16 tile into lds[128*64] with chunk-xor swizzle.
// Physical chunk (r, pc) holds logical chunk (r, pc^(r&7)).
__device__ __forceinline__ void stage256(const u16* src, size_t stride, u16* lds, int tid) {
#pragma unroll
  for (int i = 0; i < 4; ++i) {
    const int L = i * 256 + tid;       // chunk 0..1023
    const int r = L >> 3, pc = L & 7;
    const int lc = pc ^ (r & 7);
    gload16(src + (size_t)r * stride + lc * 8, lds + (size_t)(i * 256 + (tid & ~63)) * 8);
  }
}
__device__ __forceinline__ void stage512(const u16* src, size_t stride, u16* lds, int tid) {
#pragma unroll
  for (int i = 0; i < 2; ++i) {
    const int L = i * 512 + tid;
    const int r = L >> 3, pc = L & 7;
    const int lc = pc ^ (r & 7);
    gload16(src + (size_t)r * stride + lc * 8, lds + (size_t)(i * 512 + (tid & ~63)) * 8);
  }
}
// read logical chunk kc of row from a swizzled 128x64 tile
#define TILE_AT(lds, row, kc) \
  (*(const bf16x8*)&(lds)[((((row) << 3) + ((kc) ^ ((row) & 7)))) << 3])

// ---------- kernel 1: cast hidden_states fp32 -> bf16 ----------
__global__ void k_cast(const float* __restrict__ src, u16* __restrict__ dst, int n8) {
  int idx = blockIdx.x * 256 + threadIdx.x;
  if (idx >= n8) return;
  const float4* s = (const float4*)src + (size_t)idx * 2;
  float4 a = s[0], b = s[1];
  bf16x8 o;
  o[0] = (short)f2bf(a.x); o[1] = (short)f2bf(a.y);
  o[2] = (short)f2bf(a.z); o[3] = (short)f2bf(a.w);
  o[4] = (short)f2bf(b.x); o[5] = (short)f2bf(b.y);
  o[6] = (short)f2bf(b.z); o[7] = (short)f2bf(b.w);
  *(bf16x8*)(dst + (size_t)idx * 8) = o;
}

// ---------- kernel 2: transpose+cast weight: Wt[j][d] = bf16(W[d][j]) ----------
__global__ void k_wtrans(const float* __restrict__ W, u16* __restrict__ Wt) {
  __shared__ u16 tile[32][33];
  int bd = blockIdx.x >> 5, bj = blockIdx.x & 31;
  int tx = threadIdx.x & 31, ty = threadIdx.x >> 5;
#pragma unroll
  for (int i = 0; i < 32; i += 8)
    tile[ty + i][tx] = f2bf(W[(size_t)(bd * 32 + ty + i) * 1024 + bj * 32 + tx]);
  __syncthreads();
#pragma unroll
  for (int i = 0; i < 32; i += 8)
    Wt[(size_t)(bj * 32 + ty + i) * 1024 + bd * 32 + tx] = tile[tx][ty + i];
}

// ---------- kernel 3: zero output ----------
__global__ void k_zero(float4* __restrict__ p, int n4) {
  int idx = blockIdx.x * 256 + threadIdx.x;
  if (idx < n4) p[idx] = make_float4(0.f, 0.f, 0.f, 0.f);
}

// ---------- kernel 4: fused QKV GEMM (async LDS staging) ----------
__global__ __launch_bounds__(256, 2) void k_qkv(
    const u16* __restrict__ hsb, const u16* __restrict__ Wt,
    const float* __restrict__ bq, const float* __restrict__ bk, const float* __restrict__ bv,
    u16* __restrict__ Qb, u16* __restrict__ Kb, u16* __restrict__ Vt) {
  __shared__ u16 a_lds[128 * 64];
  __shared__ u16 b_lds[128 * 64];
  const int tid = threadIdx.x;
  const int lane = tid & 63, wid = tid >> 6;
  const int l15 = lane & 15, quad = lane >> 4;
  const int wr = wid >> 1, wc = wid & 1;
  const int bx = blockIdx.x & 31;
  const int by = blockIdx.x >> 5;
  const int Mbase = bx * 128;
  const int widx = by >> 3;               // 0=Q 1=K 2=V
  const int Nloc = (by & 7) * 128;

  f32x4 acc[4][4];
#pragma unroll
  for (int i = 0; i < 4; ++i)
#pragma unroll
    for (int j = 0; j < 4; ++j) acc[i][j] = (f32x4){0.f, 0.f, 0.f, 0.f};

  const u16* asrc = hsb + (size_t)Mbase * 1024;
  const u16* bsrc = Wt + (size_t)widx * 1048576 + (size_t)Nloc * 1024;

  for (int kb = 0; kb < 16; ++kb) {
    __syncthreads();
    stage256(asrc + kb * 64, 1024, a_lds, tid);
    stage256(bsrc + kb * 64, 1024, b_lds, tid);
    __syncthreads();
#pragma unroll
    for (int ks = 0; ks < 2; ++ks) {
      const int kc = ks * 4 + quad;
      bf16x8 af[4], bfr[4];
#pragma unroll
      for (int mt = 0; mt < 4; ++mt) af[mt] = TILE_AT(a_lds, wr * 64 + mt * 16 + l15, kc);
#pragma unroll
      for (int nt = 0; nt < 4; ++nt) bfr[nt] = TILE_AT(b_lds, wc * 64 + nt * 16 + l15, kc);
#pragma unroll
      for (int mt = 0; mt < 4; ++mt)
#pragma unroll
        for (int nt = 0; nt < 4; ++nt)
          acc[mt][nt] = MFMA16(af[mt], bfr[nt], acc[mt][nt]);
    }
  }
  const float* bias = (widx == 0) ? bq : ((widx == 1) ? bk : bv);
#pragma unroll
  for (int nt = 0; nt < 4; ++nt) {
    const int jloc = Nloc + wc * 64 + nt * 16 + l15;
    const float bias_v = bias[jloc];
#pragma unroll
    for (int mt = 0; mt < 4; ++mt) {
      const int Mr0 = Mbase + wr * 64 + mt * 16 + quad * 4;
      if (widx == 2) {
        const int b = Mr0 >> 11, mseq = Mr0 & 2047;
        const int g = jloc >> 7, h = jloc & 127;
        s16x4 pk;
#pragma unroll
        for (int r = 0; r < 4; ++r) pk[r] = (short)f2bf(acc[mt][nt][r] + bias_v);
        *(s16x4*)(Vt + (((size_t)b * 8 + g) * 128 + h) * 2048 + mseq) = pk;
      } else {
        u16* dst = (widx == 0) ? Qb : Kb;
#pragma unroll
        for (int r = 0; r < 4; ++r)
          dst[(size_t)(Mr0 + r) * 1024 + jloc] = f2bf(acc[mt][nt][r] + bias_v);
      }
    }
  }
}

// ---------- kernel 5: scores + softmax-over-g -> Pt[b][g][n][m-half] ----------
// grid 2048 = 8mt (XCD-pinned) x 128nt x 2b; 8 waves; wave owns 16m x 16n x 8g.
// LDS = 32KB Q tile -> up to 4 blocks/CU resident (32 waves = full occupancy).
__global__ __launch_bounds__(512, 2) void k_score(
    const u16* __restrict__ Qb, const u16* __restrict__ Kb,
    u16* __restrict__ Pt, int mh) {
  __shared__ u16 q_lds[16 * 1024];  // [n][h], 16B chunks xor-swizzled by (n&7)
  const int tid = threadIdx.x;
  const int w = tid >> 6;
  const int lane = tid & 63;
  const int l15 = lane & 15, quad = lane >> 4;
  const int bx = blockIdx.x;
  const int mt = bx & 7;
  const int nt = (bx >> 3) & 127;
  const int bcoord = bx >> 10;
  const int nbase = nt * 16;
  const int mloc = mt * 128;
  const int mglob = mh * 1024 + mloc;
  const size_t boff = (size_t)bcoord * 2048;

  // stage Q tile 16 x 1024
#pragma unroll
  for (int i = 0; i < 4; ++i) {
    int idx = tid + i * 512;
    int r = idx >> 7, c = idx & 127;
    bf16x8 v = *(const bf16x8*)(Qb + (boff + nbase + r) * 1024 + c * 8);
    *(bf16x8*)&q_lds[r * 1024 + ((c ^ (r & 7)) << 3)] = v;
  }
  __syncthreads();

  f32x4 sacc[8];
#pragma unroll
  for (int g = 0; g < 8; ++g) sacc[g] = (f32x4){0.f, 0.f, 0.f, 0.f};

  const u16* kp = Kb + (boff + mglob + w * 16 + l15) * 1024 + quad * 8;
#pragma unroll
  for (int g = 0; g < 8; ++g) {
#pragma unroll
    for (int ks = 0; ks < 4; ++ks) {
      const int hoff = g * 128 + ks * 32 + quad * 8;
      bf16x8 kf = *(const bf16x8*)(kp + g * 128 + ks * 32);
      bf16x8 qf = *(const bf16x8*)&q_lds[l15 * 1024 + (((hoff >> 3) ^ (l15 & 7)) << 3)];
      sacc[g] = MFMA16(kf, qf, sacc[g]);  // D[m][n]
    }
  }
  // softmax over g (register-local)
#pragma unroll
  for (int r = 0; r < 4; ++r) {
    float s[8];
#pragma unroll
    for (int g = 0; g < 8; ++g) s[g] = sacc[g][r] * 0.03125f;
    float mx = s[0];
#pragma unroll
    for (int g = 1; g < 8; ++g) mx = fmaxf(mx, s[g]);
    float sum = 0.f;
#pragma unroll
    for (int g = 0; g < 8; ++g) { s[g] = __expf(s[g] - mx); sum += s[g]; }
    const float rs = 1.0f / sum;
#pragma unroll
    for (int g = 0; g < 8; ++g) sacc[g][r] = s[g] * rs;
  }
  // store Pt[b][g][n][m-half]
  const int mcol = mloc + w * 16 + quad * 4;
#pragma unroll
  for (int g = 0; g < 8; ++g) {
    const size_t gbase = ((size_t)(bcoord * 8 + g) * 2048) * 1024;
    s16x4 pk;
#pragma unroll
    for (int r = 0; r < 4; ++r) pk[r] = (short)f2bf(sacc[g][r]);
    *(s16x4*)(Pt + gbase + (size_t)(nbase + l15) * 1024 + mcol) = pk;
  }
}

// ---------- kernel 6: PV GEMM, async LDS staging ----------
// grid 512 = 8g (XCD-pinned) x 2ksp x 16mt x 2b; 512 thr = 8 waves (4 wr x 2 wc).
__global__ __launch_bounds__(512, 4) void k_pv(
    const u16* __restrict__ Pt, const u16* __restrict__ Vt,
    float* __restrict__ out, int mh) {
  __shared__ u16 a_lds[128 * 64];
  __shared__ u16 b_lds[128 * 64];
  const int tid = threadIdx.x;
  const int lane = tid & 63, wid = tid >> 6;
  const int l15 = lane & 15, quad = lane >> 4;
  const int wr = wid >> 1, wc = wid & 1;
  const int bx = blockIdx.x;
  const int g = bx & 7;
  const int ksp = (bx >> 3) & 1;
  const int mt = (bx >> 4) & 15;
  const int bcoord = bx >> 8;
  const int nbase = mt * 128;
  const int kh0 = ksp * 512;

  const u16* asrc = Pt + (size_t)(bcoord * 8 + g) * 2048 * 1024 + (size_t)nbase * 1024 + kh0;
  const u16* bsrc = Vt + (size_t)(bcoord * 8 + g) * 128 * 2048 + mh * 1024 + kh0;

  f32x4 acc[2][4];
#pragma unroll
  for (int i = 0; i < 2; ++i)
#pragma unroll
    for (int j = 0; j < 4; ++j) acc[i][j] = (f32x4){0.f, 0.f, 0.f, 0.f};

  for (int kb = 0; kb < 8; ++kb) {
    __syncthreads();
    stage512(asrc + kb * 64, 1024, a_lds, tid);
    stage512(bsrc + kb * 64, 2048, b_lds, tid);
    __syncthreads();
#pragma unroll
    for (int ks = 0; ks < 2; ++ks) {
      const int kc = ks * 4 + quad;
      bf16x8 af[2], bfr[4];
#pragma unroll
      for (int mf = 0; mf < 2; ++mf) af[mf] = TILE_AT(a_lds, wr * 32 + mf * 16 + l15, kc);
#pragma unroll
      for (int nf = 0; nf < 4; ++nf) bfr[nf] = TILE_AT(b_lds, wc * 64 + nf * 16 + l15, kc);
#pragma unroll
      for (int mf = 0; mf < 2; ++mf)
#pragma unroll
        for (int nf = 0; nf < 4; ++nf)
          acc[mf][nf] = MFMA16(af[mf], bfr[nf], acc[mf][nf]);
    }
  }
#pragma unroll
  for (int mf = 0; mf < 2; ++mf)
#pragma unroll
    for (int nf = 0; nf < 4; ++nf)
#pragma unroll
      for (int r = 0; r < 4; ++r) {
        const int nrow = nbase + wr * 32 + mf * 16 + quad * 4 + r;
        const int col = g * 128 + wc * 64 + nf * 16 + l15;
        atomicAdd(out + ((size_t)bcoord * 2048 + nrow) * 1024 + col, acc[mf][nf][r]);
      }
}

extern "C" void kernel_launch(void* const* d_in, const int* in_sizes, int n_in,
                              void* d_out, int out_size, void* d_ws, size_t ws_size,
                              hipStream_t stream) {
  const float* hs = (const float*)d_in[0];
  const float* Wq = (const float*)d_in[1];
  const float* bq = (const float*)d_in[2];
  const float* Wk = (const float*)d_in[3];
  const float* bk = (const float*)d_in[4];
  const float* Wv = (const float*)d_in[5];
  const float* bv = (const float*)d_in[6];
  float* out = (float*)d_out;

  u16* ws = (u16*)d_ws;
  u16* hsb = ws;                   // 4096x1024
  u16* Wt  = ws + 4194304;         // 3 x 1024x1024 (j-major)
  u16* Qb  = ws + 7340032;         // [b][n][1024]
  u16* Kb  = ws + 11534336;        // [b][m][1024]
  u16* Vt  = ws + 15728640;        // [b][g][h][m] = [2][8][128][2048]
  u16* Pt  = ws + 19922944;        // [b][g][n][m-half] = [2][8][2048][1024]

  k_cast<<<2048, 256, 0, stream>>>(hs, hsb, 524288);
  k_wtrans<<<1024, 256, 0, stream>>>(Wq, Wt);
  k_wtrans<<<1024, 256, 0, stream>>>(Wk, Wt + 1048576);
  k_wtrans<<<1024, 256, 0, stream>>>(Wv, Wt + 2097152);
  k_qkv<<<32 * 24, 256, 0, stream>>>(hsb, Wt, bq, bk, bv, Qb, Kb, Vt);
  k_zero<<<4096, 256, 0, stream>>>((float4*)out, 1048576);
  for (int mh = 0; mh < 2; ++mh) {
    k_score<<<2048, 512, 0, stream>>>(Qb, Kb, Pt, mh);
    k_pv<<<512, 512, 0, stream>>>(Pt, Vt, out, mh);
  }
}

// Round 7
// 284.372 us; speedup vs baseline: 1.3118x; 1.2922x over previous
//
#include <hip/hip_runtime.h>
#include <stdint.h>

typedef unsigned short u16;
typedef __attribute__((ext_vector_type(8))) short bf16x8;
typedef __attribute__((ext_vector_type(4))) short s16x4;
typedef __attribute__((ext_vector_type(4))) float f32x4;

#define MFMA16(a,b,c) __builtin_amdgcn_mfma_f32_16x16x32_bf16((a),(b),(c),0,0,0)

__device__ __forceinline__ u16 f2bf(float f) {
  union { float f; uint32_t u; } v; v.f = f;
  return (u16)((v.u + 0x7fffu + ((v.u >> 16) & 1u)) >> 16);
}

// async 16B global->LDS (lds dest = wave-uniform base + lane*16)
__device__ __forceinline__ void gload16(const void* g, void* l) {
  __builtin_amdgcn_global_load_lds((const __attribute__((address_space(1))) void*)g,
                                   (__attribute__((address_space(3))) void*)l, 16, 0, 0);
}

// Stage a 128x64 bf16 tile into lds[128*64] with chunk-xor swizzle.
// Physical chunk (r, pc) holds logical chunk (r, pc^(r&7)).
__device__ __forceinline__ void stage256(const u16* src, size_t stride, u16* lds, int tid) {
#pragma unroll
  for (int i = 0; i < 4; ++i) {
    const int L = i * 256 + tid;       // chunk 0..1023
    const int r = L >> 3, pc = L & 7;
    const int lc = pc ^ (r & 7);
    gload16(src + (size_t)r * stride + lc * 8, lds + (size_t)(i * 256 + (tid & ~63)) * 8);
  }
}
__device__ __forceinline__ void stage512(const u16* src, size_t stride, u16* lds, int tid) {
#pragma unroll
  for (int i = 0; i < 2; ++i) {
    const int L = i * 512 + tid;
    const int r = L >> 3, pc = L & 7;
    const int lc = pc ^ (r & 7);
    gload16(src + (size_t)r * stride + lc * 8, lds + (size_t)(i * 512 + (tid & ~63)) * 8);
  }
}
// read logical chunk kc of row from a swizzled 128x64 tile
#define TILE_AT(lds, row, kc) \
  (*(const bf16x8*)&(lds)[((((row) << 3) + ((kc) ^ ((row) & 7)))) << 3])

// ---------- kernel 1: cast hidden_states fp32 -> bf16 ----------
__global__ void k_cast(const float* __restrict__ src, u16* __restrict__ dst, int n8) {
  int idx = blockIdx.x * 256 + threadIdx.x;
  if (idx >= n8) return;
  const float4* s = (const float4*)src + (size_t)idx * 2;
  float4 a = s[0], b = s[1];
  bf16x8 o;
  o[0] = (short)f2bf(a.x); o[1] = (short)f2bf(a.y);
  o[2] = (short)f2bf(a.z); o[3] = (short)f2bf(a.w);
  o[4] = (short)f2bf(b.x); o[5] = (short)f2bf(b.y);
  o[6] = (short)f2bf(b.z); o[7] = (short)f2bf(b.w);
  *(bf16x8*)(dst + (size_t)idx * 8) = o;
}

// ---------- kernel 2: transpose+cast weight: Wt[j][d] = bf16(W[d][j]) ----------
__global__ void k_wtrans(const float* __restrict__ W, u16* __restrict__ Wt) {
  __shared__ u16 tile[32][33];
  int bd = blockIdx.x >> 5, bj = blockIdx.x & 31;
  int tx = threadIdx.x & 31, ty = threadIdx.x >> 5;
#pragma unroll
  for (int i = 0; i < 32; i += 8)
    tile[ty + i][tx] = f2bf(W[(size_t)(bd * 32 + ty + i) * 1024 + bj * 32 + tx]);
  __syncthreads();
#pragma unroll
  for (int i = 0; i < 32; i += 8)
    Wt[(size_t)(bj * 32 + ty + i) * 1024 + bd * 32 + tx] = tile[tx][ty + i];
}

// ---------- kernel 3: zero output ----------
__global__ void k_zero(float4* __restrict__ p, int n4) {
  int idx = blockIdx.x * 256 + threadIdx.x;
  if (idx < n4) p[idx] = make_float4(0.f, 0.f, 0.f, 0.f);
}

// ---------- kernel 4: fused QKV GEMM (async LDS staging) ----------
__global__ __launch_bounds__(256, 2) void k_qkv(
    const u16* __restrict__ hsb, const u16* __restrict__ Wt,
    const float* __restrict__ bq, const float* __restrict__ bk, const float* __restrict__ bv,
    u16* __restrict__ Qb, u16* __restrict__ Kb, u16* __restrict__ Vt) {
  __shared__ u16 a_lds[128 * 64];
  __shared__ u16 b_lds[128 * 64];
  const int tid = threadIdx.x;
  const int lane = tid & 63, wid = tid >> 6;
  const int l15 = lane & 15, quad = lane >> 4;
  const int wr = wid >> 1, wc = wid & 1;
  const int bx = blockIdx.x & 31;
  const int by = blockIdx.x >> 5;
  const int Mbase = bx * 128;
  const int widx = by >> 3;               // 0=Q 1=K 2=V
  const int Nloc = (by & 7) * 128;

  f32x4 acc[4][4];
#pragma unroll
  for (int i = 0; i < 4; ++i)
#pragma unroll
    for (int j = 0; j < 4; ++j) acc[i][j] = (f32x4){0.f, 0.f, 0.f, 0.f};

  const u16* asrc = hsb + (size_t)Mbase * 1024;
  const u16* bsrc = Wt + (size_t)widx * 1048576 + (size_t)Nloc * 1024;

  for (int kb = 0; kb < 16; ++kb) {
    __syncthreads();
    stage256(asrc + kb * 64, 1024, a_lds, tid);
    stage256(bsrc + kb * 64, 1024, b_lds, tid);
    __syncthreads();
#pragma unroll
    for (int ks = 0; ks < 2; ++ks) {
      const int kc = ks * 4 + quad;
      bf16x8 af[4], bfr[4];
#pragma unroll
      for (int mt = 0; mt < 4; ++mt) af[mt] = TILE_AT(a_lds, wr * 64 + mt * 16 + l15, kc);
#pragma unroll
      for (int nt = 0; nt < 4; ++nt) bfr[nt] = TILE_AT(b_lds, wc * 64 + nt * 16 + l15, kc);
#pragma unroll
      for (int mt = 0; mt < 4; ++mt)
#pragma unroll
        for (int nt = 0; nt < 4; ++nt)
          acc[mt][nt] = MFMA16(af[mt], bfr[nt], acc[mt][nt]);
    }
  }
  const float* bias = (widx == 0) ? bq : ((widx == 1) ? bk : bv);
#pragma unroll
  for (int nt = 0; nt < 4; ++nt) {
    const int jloc = Nloc + wc * 64 + nt * 16 + l15;
    const float bias_v = bias[jloc];
#pragma unroll
    for (int mt = 0; mt < 4; ++mt) {
      const int Mr0 = Mbase + wr * 64 + mt * 16 + quad * 4;
      if (widx == 2) {
        const int b = Mr0 >> 11, mseq = Mr0 & 2047;
        const int g = jloc >> 7, h = jloc & 127;
        s16x4 pk;
#pragma unroll
        for (int r = 0; r < 4; ++r) pk[r] = (short)f2bf(acc[mt][nt][r] + bias_v);
        *(s16x4*)(Vt + (((size_t)b * 8 + g) * 128 + h) * 2048 + mseq) = pk;
      } else {
        u16* dst = (widx == 0) ? Qb : Kb;
#pragma unroll
        for (int r = 0; r < 4; ++r)
          dst[(size_t)(Mr0 + r) * 1024 + jloc] = f2bf(acc[mt][nt][r] + bias_v);
      }
    }
  }
}

// ---------- kernel 5: scores + softmax-over-g -> Pt[b][g][n][m-half] ----------
// grid 512 = 8mt (XCD-pinned) x 32nt x 2b; 8 waves; wave owns 16m x 64n x 8g.
// n_tile=64 halves the L3 K-re-read traffic vs n_tile=32 (the measured
// bottleneck: all k_score variants run at ~7-8 TB/s of cache traffic).
// Q tile 128 KB LDS -> 1 block/CU; sacc = 128 AGPRs, launch_bounds (512,2)
// caps unified regs at 256 so the 8-wave block fits at 2 waves/SIMD.
__global__ __launch_bounds__(512, 2) void k_score(
    const u16* __restrict__ Qb, const u16* __restrict__ Kb,
    u16* __restrict__ Pt, int mh) {
  __shared__ u16 q_lds[64 * 1024];  // [n][h], 16B chunks xor-swizzled by (n&7)
  const int tid = threadIdx.x;
  const int w = tid >> 6;
  const int lane = tid & 63;
  const int l15 = lane & 15, quad = lane >> 4;
  const int bx = blockIdx.x;
  const int mt = bx & 7;
  const int nt = (bx >> 3) & 31;
  const int bcoord = bx >> 8;
  const int nbase = nt * 64;
  const int mloc = mt * 128;
  const int mglob = mh * 1024 + mloc;
  const size_t boff = (size_t)bcoord * 2048;

  // stage Q tile 64 x 1024 (8192 16B-chunks, 16 per thread)
#pragma unroll
  for (int i = 0; i < 16; ++i) {
    int idx = tid + i * 512;
    int r = idx >> 7, c = idx & 127;
    bf16x8 v = *(const bf16x8*)(Qb + (boff + nbase + r) * 1024 + c * 8);
    *(bf16x8*)&q_lds[r * 1024 + ((c ^ (r & 7)) << 3)] = v;
  }
  __syncthreads();

  f32x4 sacc[4][8];
#pragma unroll
  for (int nf = 0; nf < 4; ++nf)
#pragma unroll
    for (int g = 0; g < 8; ++g) sacc[nf][g] = (f32x4){0.f, 0.f, 0.f, 0.f};

  const u16* kp = Kb + (boff + mglob + w * 16 + l15) * 1024 + quad * 8;
#pragma unroll
  for (int g = 0; g < 8; ++g) {
#pragma unroll
    for (int ks = 0; ks < 4; ++ks) {
      bf16x8 kf = *(const bf16x8*)(kp + g * 128 + ks * 32);
      const int kc = g * 16 + ks * 4 + quad;   // logical h-chunk
#pragma unroll
      for (int nf = 0; nf < 4; ++nf) {
        const int row = nf * 16 + l15;
        bf16x8 qf = *(const bf16x8*)&q_lds[row * 1024 + ((kc ^ (row & 7)) << 3)];
        sacc[nf][g] = MFMA16(kf, qf, sacc[nf][g]);  // D[m][n]
      }
    }
  }
  // softmax over g (register-local)
#pragma unroll
  for (int nf = 0; nf < 4; ++nf)
#pragma unroll
    for (int r = 0; r < 4; ++r) {
      float s[8];
#pragma unroll
      for (int g = 0; g < 8; ++g) s[g] = sacc[nf][g][r] * 0.03125f;
      float mx = s[0];
#pragma unroll
      for (int g = 1; g < 8; ++g) mx = fmaxf(mx, s[g]);
      float sum = 0.f;
#pragma unroll
      for (int g = 0; g < 8; ++g) { s[g] = __expf(s[g] - mx); sum += s[g]; }
      const float rs = 1.0f / sum;
#pragma unroll
      for (int g = 0; g < 8; ++g) sacc[nf][g][r] = s[g] * rs;
    }
  // store Pt[b][g][n][m-half]
  const int mcol = mloc + w * 16 + quad * 4;
#pragma unroll
  for (int g = 0; g < 8; ++g) {
    const size_t gbase = ((size_t)(bcoord * 8 + g) * 2048) * 1024;
#pragma unroll
    for (int nf = 0; nf < 4; ++nf) {
      s16x4 pk;
#pragma unroll
      for (int r = 0; r < 4; ++r) pk[r] = (short)f2bf(sacc[nf][g][r]);
      *(s16x4*)(Pt + gbase + (size_t)(nbase + nf * 16 + l15) * 1024 + mcol) = pk;
    }
  }
}

// ---------- kernel 6: PV GEMM, async LDS staging ----------
// grid 512 = 8g (XCD-pinned) x 2ksp x 16mt x 2b; 512 thr = 8 waves (4 wr x 2 wc).
__global__ __launch_bounds__(512, 4) void k_pv(
    const u16* __restrict__ Pt, const u16* __restrict__ Vt,
    float* __restrict__ out, int mh) {
  __shared__ u16 a_lds[128 * 64];
  __shared__ u16 b_lds[128 * 64];
  const int tid = threadIdx.x;
  const int lane = tid & 63, wid = tid >> 6;
  const int l15 = lane & 15, quad = lane >> 4;
  const int wr = wid >> 1, wc = wid & 1;
  const int bx = blockIdx.x;
  const int g = bx & 7;
  const int ksp = (bx >> 3) & 1;
  const int mt = (bx >> 4) & 15;
  const int bcoord = bx >> 8;
  const int nbase = mt * 128;
  const int kh0 = ksp * 512;

  const u16* asrc = Pt + (size_t)(bcoord * 8 + g) * 2048 * 1024 + (size_t)nbase * 1024 + kh0;
  const u16* bsrc = Vt + (size_t)(bcoord * 8 + g) * 128 * 2048 + mh * 1024 + kh0;

  f32x4 acc[2][4];
#pragma unroll
  for (int i = 0; i < 2; ++i)
#pragma unroll
    for (int j = 0; j < 4; ++j) acc[i][j] = (f32x4){0.f, 0.f, 0.f, 0.f};

  for (int kb = 0; kb < 8; ++kb) {
    __syncthreads();
    stage512(asrc + kb * 64, 1024, a_lds, tid);
    stage512(bsrc + kb * 64, 2048, b_lds, tid);
    __syncthreads();
#pragma unroll
    for (int ks = 0; ks < 2; ++ks) {
      const int kc = ks * 4 + quad;
      bf16x8 af[2], bfr[4];
#pragma unroll
      for (int mf = 0; mf < 2; ++mf) af[mf] = TILE_AT(a_lds, wr * 32 + mf * 16 + l15, kc);
#pragma unroll
      for (int nf = 0; nf < 4; ++nf) bfr[nf] = TILE_AT(b_lds, wc * 64 + nf * 16 + l15, kc);
#pragma unroll
      for (int mf = 0; mf < 2; ++mf)
#pragma unroll
        for (int nf = 0; nf < 4; ++nf)
          acc[mf][nf] = MFMA16(af[mf], bfr[nf], acc[mf][nf]);
    }
  }
#pragma unroll
  for (int mf = 0; mf < 2; ++mf)
#pragma unroll
    for (int nf = 0; nf < 4; ++nf)
#pragma unroll
      for (int r = 0; r < 4; ++r) {
        const int nrow = nbase + wr * 32 + mf * 16 + quad * 4 + r;
        const int col = g * 128 + wc * 64 + nf * 16 + l15;
        atomicAdd(out + ((size_t)bcoord * 2048 + nrow) * 1024 + col, acc[mf][nf][r]);
      }
}

extern "C" void kernel_launch(void* const* d_in, const int* in_sizes, int n_in,
                              void* d_out, int out_size, void* d_ws, size_t ws_size,
                              hipStream_t stream) {
  const float* hs = (const float*)d_in[0];
  const float* Wq = (const float*)d_in[1];
  const float* bq = (const float*)d_in[2];
  const float* Wk = (const float*)d_in[3];
  const float* bk = (const float*)d_in[4];
  const float* Wv = (const float*)d_in[5];
  const float* bv = (const float*)d_in[6];
  float* out = (float*)d_out;

  u16* ws = (u16*)d_ws;
  u16* hsb = ws;                   // 4096x1024
  u16* Wt  = ws + 4194304;         // 3 x 1024x1024 (j-major)
  u16* Qb  = ws + 7340032;         // [b][n][1024]
  u16* Kb  = ws + 11534336;        // [b][m][1024]
  u16* Vt  = ws + 15728640;        // [b][g][h][m] = [2][8][128][2048]
  u16* Pt  = ws + 19922944;        // [b][g][n][m-half] = [2][8][2048][1024]

  k_cast<<<2048, 256, 0, stream>>>(hs, hsb, 524288);
  k_wtrans<<<1024, 256, 0, stream>>>(Wq, Wt);
  k_wtrans<<<1024, 256, 0, stream>>>(Wk, Wt + 1048576);
  k_wtrans<<<1024, 256, 0, stream>>>(Wv, Wt + 2097152);
  k_qkv<<<32 * 24, 256, 0, stream>>>(hsb, Wt, bq, bk, bv, Qb, Kb, Vt);
  k_zero<<<4096, 256, 0, stream>>>((float4*)out, 1048576);
  for (int mh = 0; mh < 2; ++mh) {
    k_score<<<512, 512, 0, stream>>>(Qb, Kb, Pt, mh);
    k_pv<<<512, 512, 0, stream>>>(Pt, Vt, out, mh);
  }
}